// Round 18
// baseline (154.103 us; speedup 1.0000x reference)
//
#include <hip/hip_runtime.h>
#include <hip/hip_bf16.h>
#include <stdint.h>

typedef __hip_bfloat16 bf16;
typedef __attribute__((ext_vector_type(8))) short bf16x8;
typedef __attribute__((ext_vector_type(4))) float f32x4;
typedef __attribute__((ext_vector_type(8))) unsigned short u16x8;
typedef __attribute__((ext_vector_type(4))) unsigned short u16x4;

#define SLEN 2048
#define ED   1024
#define NB   4
#define AS1 __attribute__((address_space(1)))
#define AS3 __attribute__((address_space(3)))
#define SB0() __builtin_amdgcn_sched_barrier(0)

static __device__ __forceinline__ unsigned short f2bf(float f) {
    return __builtin_bit_cast(unsigned short, __float2bfloat16(f));
}

// ============================================================================
// gemm8p (MEASURED PASSING R14-R17). 8-phase 256x256 / BK=64 / 512 thr.
// DO NOT MODIFY.
// ============================================================================
__device__ __forceinline__ void gemm8p(
    const char* __restrict__ aT, int lda,
    const char* __restrict__ bT, int ldb,
    int nkt, char* sm, int tid, f32x4 (&acc)[8][4])
{
    const int lane = tid & 63, wave = tid >> 6;
    const int wm = wave >> 2, wn = wave & 3;
    const int fr = lane & 15, kc = lane >> 4;

    auto SU = [&](int isB, int kh, int Tn) {
        char* dst = sm + (Tn & 1) * 65536 + isB * 32768 + kh * 16384;
        const char* g = isB ? bT : aT;
        const int ld = isB ? ldb : lda;
#pragma unroll
        for (int j = 0; j < 2; ++j) {
            int rid = j * 512 + tid;
            int row = rid >> 2, c = rid & 3;
            const char* src = g + (size_t)row * ld + Tn * 128 + kh * 64
                            + ((c ^ ((row >> 1) & 3)) * 16);
            __builtin_amdgcn_global_load_lds(
                (const AS1 uint32_t*)src,
                (AS3 uint32_t*)(dst + (j * 512 + wave * 64) * 16), 16, 0, 0);
        }
    };
    auto RDA = [&](int T, int kh, bf16x8 (&a)[8]) {
        const char* pa = sm + (T & 1) * 65536 + kh * 16384;
#pragma unroll
        for (int i = 0; i < 8; ++i) {
            int row = wm * 128 + i * 16 + fr;
            a[i] = *(const bf16x8*)(pa + row * 64 + ((kc ^ ((row >> 1) & 3)) * 16));
        }
    };
    auto RDB = [&](int T, int kh, int nh, bf16x8 (&b)[2]) {
        const char* pb = sm + (T & 1) * 65536 + 32768 + kh * 16384;
#pragma unroll
        for (int n = 0; n < 2; ++n) {
            int row = wn * 64 + nh * 32 + n * 16 + fr;
            b[n] = *(const bf16x8*)(pb + row * 64 + ((kc ^ ((row >> 1) & 3)) * 16));
        }
    };
    auto MM = [&](bf16x8 (&a)[8], bf16x8 (&b)[2], int nh) {
        __builtin_amdgcn_s_setprio(1);
#pragma unroll
        for (int i = 0; i < 8; ++i)
#pragma unroll
            for (int n = 0; n < 2; ++n)
                acc[i][nh * 2 + n] = __builtin_amdgcn_mfma_f32_16x16x32_bf16(
                    a[i], b[n], acc[i][nh * 2 + n], 0, 0, 0);
        __builtin_amdgcn_s_setprio(0);
    };

    SU(0, 0, 0); SU(1, 0, 0); SU(0, 1, 0); SU(1, 1, 0);
    SU(0, 0, 1); SU(1, 0, 1); SU(0, 1, 1);
    asm volatile("s_waitcnt vmcnt(6)" ::: "memory");
    SB0();
    __builtin_amdgcn_s_barrier();

    for (int T = 0; T < nkt; ++T) {
        const bool p1 = (T + 1 < nkt), p2 = (T + 2 < nkt);
        bf16x8 a[8], b[2];
        RDA(T, 0, a); RDB(T, 0, 0, b);
        if (p1) SU(1, 1, T + 1);
        SB0(); __builtin_amdgcn_s_barrier();
        asm volatile("s_waitcnt lgkmcnt(0)" ::: "memory");
        SB0();
        MM(a, b, 0);
        SB0(); __builtin_amdgcn_s_barrier();
        RDB(T, 0, 1, b);
        if (p2) SU(0, 0, T + 2);
        SB0(); __builtin_amdgcn_s_barrier();
        asm volatile("s_waitcnt lgkmcnt(0)" ::: "memory");
        SB0();
        MM(a, b, 1);
        SB0(); __builtin_amdgcn_s_barrier();
        RDA(T, 1, a); RDB(T, 1, 0, b);
        if (p2) SU(1, 0, T + 2);
        SB0(); __builtin_amdgcn_s_barrier();
        asm volatile("s_waitcnt lgkmcnt(0)" ::: "memory");
        SB0();
        MM(a, b, 0);
        SB0(); __builtin_amdgcn_s_barrier();
        RDB(T, 1, 1, b);
        if (p2) SU(0, 1, T + 2);
        if (T < nkt - 2) asm volatile("s_waitcnt vmcnt(6)" ::: "memory");
        else             asm volatile("s_waitcnt vmcnt(0)" ::: "memory");
        SB0(); __builtin_amdgcn_s_barrier();
        asm volatile("s_waitcnt lgkmcnt(0)" ::: "memory");
        SB0();
        MM(a, b, 1);
        SB0(); __builtin_amdgcn_s_barrier();
    }
}

// ============================================================================
// gemm_core8 (MEASURED PASSING R7): 256x128 / 512 thr. DO NOT MODIFY.
// ============================================================================
__device__ __forceinline__ void gemm_core8(
    const char* __restrict__ aT, int lda,
    const char* __restrict__ bT, int ldb,
    int nkt, char* sm, int tid, f32x4 (&acc)[4][4])
{
    const int lane = tid & 63, wave = tid >> 6;
    const int wm = wave >> 1, wn = wave & 1;
    const int fr = lane & 15, kc = lane >> 4;

    auto STAGE = [&](int kh, int Tn) {
        char* buf = sm + (Tn & 1) * 49152;
#pragma unroll
        for (int j = 0; j < 2; ++j) {
            int rid = j * 512 + tid;
            int row = rid >> 2, c = rid & 3;
            const char* src = aT + (size_t)row * lda + Tn * 128 + kh * 64
                            + ((c ^ ((row >> 1) & 3)) * 16);
            __builtin_amdgcn_global_load_lds(
                (const AS1 uint32_t*)src,
                (AS3 uint32_t*)(buf + kh * 16384 + (j * 512 + wave * 64) * 16),
                16, 0, 0);
        }
        {
            int row = tid >> 2, c = tid & 3;
            const char* src = bT + (size_t)row * ldb + Tn * 128 + kh * 64
                            + ((c ^ ((row >> 1) & 3)) * 16);
            __builtin_amdgcn_global_load_lds(
                (const AS1 uint32_t*)src,
                (AS3 uint32_t*)(buf + 32768 + kh * 8192 + (wave * 64) * 16),
                16, 0, 0);
        }
    };
    auto RD = [&](int T, int kh, bf16x8 (&a)[4], bf16x8 (&b)[4]) {
        const char* buf = sm + (T & 1) * 49152;
#pragma unroll
        for (int i = 0; i < 4; ++i) {
            int row = wm * 64 + i * 16 + fr;
            a[i] = *(const bf16x8*)(buf + kh * 16384 + row * 64
                                    + ((kc ^ ((row >> 1) & 3)) * 16));
        }
#pragma unroll
        for (int i = 0; i < 4; ++i) {
            int row = wn * 64 + i * 16 + fr;
            b[i] = *(const bf16x8*)(buf + 32768 + kh * 8192 + row * 64
                                    + ((kc ^ ((row >> 1) & 3)) * 16));
        }
    };
    auto MM = [&](bf16x8 (&a)[4], bf16x8 (&b)[4]) {
        __builtin_amdgcn_s_setprio(1);
#pragma unroll
        for (int i = 0; i < 4; ++i)
#pragma unroll
            for (int n = 0; n < 4; ++n)
                acc[i][n] = __builtin_amdgcn_mfma_f32_16x16x32_bf16(
                    a[i], b[n], acc[i][n], 0, 0, 0);
        __builtin_amdgcn_s_setprio(0);
    };

    STAGE(0, 0); STAGE(1, 0);
    asm volatile("s_waitcnt vmcnt(3)" ::: "memory");
    SB0();
    __builtin_amdgcn_s_barrier();

    bf16x8 aE[4], bE[4], aO[4], bO[4];
    for (int T = 0; T < nkt; ++T) {
        const bool pre = (T + 1 < nkt);
        RD(T, 0, aE, bE);
        SB0();
        if (pre) STAGE(0, T + 1);
        SB0();
        if (T > 0) {
            asm volatile("s_waitcnt lgkmcnt(8)" ::: "memory");
            SB0();
            MM(aO, bO);
        }
        if (pre) asm volatile("s_waitcnt vmcnt(3)" ::: "memory");
        else     asm volatile("s_waitcnt vmcnt(0)" ::: "memory");
        SB0();
        __builtin_amdgcn_s_barrier();
        RD(T, 1, aO, bO);
        SB0();
        if (pre) STAGE(1, T + 1);
        SB0();
        asm volatile("s_waitcnt lgkmcnt(8)" ::: "memory");
        SB0();
        MM(aE, bE);
        if (pre) asm volatile("s_waitcnt vmcnt(3)" ::: "memory");
        else     asm volatile("s_waitcnt vmcnt(0)" ::: "memory");
        SB0();
        __builtin_amdgcn_s_barrier();
    }
    asm volatile("s_waitcnt lgkmcnt(0)" ::: "memory");
    SB0();
    MM(aO, bO);
}

// ---------------- convert fp32 -> bf16 (x and the 3 weights) ----------------
__global__ __launch_bounds__(256) void convert_to_bf16(
    const float* __restrict__ x, const float* __restrict__ wq,
    const float* __restrict__ wk, const float* __restrict__ wv,
    bf16* __restrict__ xb, bf16* __restrict__ wqb,
    bf16* __restrict__ wkb, bf16* __restrict__ wvb)
{
    long g = (long)blockIdx.x * 256 + threadIdx.x;
    const float* src; bf16* dst; long o;
    if (g < 1048576) { src = x; dst = xb; o = g * 8; }
    else {
        long g2 = g - 1048576;
        int w = (int)(g2 >> 17);
        o = (g2 & 131071) * 8;
        src = (w == 0) ? wq : (w == 1) ? wk : wv;
        dst = (w == 0) ? wqb : (w == 1) ? wkb : wvb;
    }
    float4 v0 = *(const float4*)(src + o);
    float4 v1 = *(const float4*)(src + o + 4);
    u16x8 r;
    r[0] = f2bf(v0.x); r[1] = f2bf(v0.y); r[2] = f2bf(v0.z); r[3] = f2bf(v0.w);
    r[4] = f2bf(v1.x); r[5] = f2bf(v1.y); r[6] = f2bf(v1.z); r[7] = f2bf(v1.w);
    *(u16x8*)(dst + o) = r;
}

// ---------------- fused QKV (R17 verbatim, 59.1us measured): 512 blocks -----
__global__ __launch_bounds__(512, 2) void qkv_gemm(
    const bf16* __restrict__ xb, const bf16* __restrict__ wqb,
    const bf16* __restrict__ wkb, const bf16* __restrict__ wvb,
    bf16* __restrict__ Qb, bf16* __restrict__ Kb, bf16* __restrict__ Vt)
{
    extern __shared__ char smem[];
    int bid = blockIdx.x, tid = threadIdx.x;
    int lane = tid & 63, wave = tid >> 6;
    if (bid < 256) {
        int xcd = bid & 7, i = bid >> 3;
        int tm = (xcd << 2) | (i & 3);
        int tn = i >> 2;
        const bf16* W = (tn < 4) ? wqb : wkb;
        int tnl = tn & 3;
        f32x4 acc[8][4] = {};
        gemm8p((const char*)(xb + (size_t)tm * 256 * ED), ED * 2,
               (const char*)(W + (size_t)tnl * 256 * ED), ED * 2,
               16, smem, tid, acc);

        int wm = wave >> 2, wn = wave & 3;
        int rl = (lane >> 4) * 4, cl = lane & 15;
        bf16* C = (tn < 4) ? Qb : Kb;
#pragma unroll
        for (int mf = 0; mf < 8; ++mf)
#pragma unroll
            for (int j = 0; j < 4; ++j) {
                int r = tm * 256 + wm * 128 + mf * 16 + rl + j;
#pragma unroll
                for (int nf = 0; nf < 4; ++nf) {
                    int c = tnl * 256 + wn * 64 + nf * 16 + cl;
                    C[(size_t)r * ED + c] = __float2bfloat16(acc[mf][nf][j]);
                }
            }
    } else {
        int bid2 = bid - 256;
        int xcd = bid2 & 7, i = bid2 >> 3;
        int tm = (xcd << 2) | (i & 3);
        int tnl = i >> 2;
        f32x4 acc[4][4] = {};
        gemm_core8((const char*)(xb + (size_t)tm * 256 * ED), ED * 2,
                   (const char*)(wvb + (size_t)tnl * 128 * ED), ED * 2,
                   16, smem, tid, acc);

        int wm = wave >> 1, wn = wave & 1;
        int rl = (lane >> 4) * 4, cl = lane & 15;
#pragma unroll
        for (int mf = 0; mf < 4; ++mf)
#pragma unroll
            for (int j = 0; j < 4; ++j) {
                int r = tm * 256 + wm * 64 + mf * 16 + rl + j;
                int bb = r >> 11, s = r & 2047;
#pragma unroll
                for (int nf = 0; nf < 4; ++nf) {
                    int d = tnl * 128 + wn * 64 + nf * 16 + cl;
                    Vt[(((size_t)bb << 10) + d) * SLEN + s] = __float2bfloat16(acc[mf][nf][j]);
                }
            }
    }
}

// ---------------- scores = Q @ K^T / 32 (R15 verbatim): 36x4, 8-phase -------
__global__ __launch_bounds__(512, 2) void qk_gemm(
    const bf16* __restrict__ Qb, const bf16* __restrict__ Kb, float* __restrict__ Sc)
{
    extern __shared__ char smem[];
    int t = blockIdx.x, b = blockIdx.y, tid = threadIdx.x;
    int ti = 0;
    while ((ti + 1) * (ti + 2) / 2 <= t) ++ti;   // triangular decode, ti<=7
    int tj = t - ti * (ti + 1) / 2;
    f32x4 acc[8][4] = {};
    gemm8p((const char*)(Qb + ((size_t)b * SLEN + ti * 256) * ED), ED * 2,
           (const char*)(Kb + ((size_t)b * SLEN + tj * 256) * ED), ED * 2,
           16, smem, tid, acc);

    float* Sb = Sc + (size_t)b * SLEN * SLEN;
    int lane = tid & 63, wave = tid >> 6, wm = wave >> 2, wn = wave & 3;
    int rl = (lane >> 4) * 4, cl = lane & 15;
#pragma unroll
    for (int mf = 0; mf < 8; ++mf)
#pragma unroll
        for (int j = 0; j < 4; ++j) {
            int r = ti * 256 + wm * 128 + mf * 16 + rl + j;
#pragma unroll
            for (int nf = 0; nf < 4; ++nf) {
                int c = tj * 256 + wn * 64 + nf * 16 + cl;
                Sb[(size_t)r * SLEN + c] = acc[mf][nf][j] * 0.03125f;
            }
        }
}

// ---------------- causal row softmax (R15 verbatim, kmax-trimmed) -----------
__global__ __launch_bounds__(256) void softmax_rows(float* __restrict__ Sc)
{
    int q = blockIdx.x, b = blockIdx.y, tid = threadIdx.x;
    float* row = Sc + ((size_t)b * SLEN + q) * SLEN;
    int lane = tid & 63, wave = tid >> 6;
    __shared__ float red[4];

    float vals[8];
    float lmax = -3.0e38f;
#pragma unroll
    for (int r = 0; r < 2; ++r) {
        int i4 = tid + r * 256;
        if (i4 * 4 <= q) {
            float4 v = *(const float4*)(row + i4 * 4);
            vals[r * 4 + 0] = v.x; vals[r * 4 + 1] = v.y;
            vals[r * 4 + 2] = v.z; vals[r * 4 + 3] = v.w;
#pragma unroll
            for (int e = 0; e < 4; ++e) {
                int k = i4 * 4 + e;
                if (k <= q) lmax = fmaxf(lmax, vals[r * 4 + e]);
            }
        }
    }
#pragma unroll
    for (int o = 32; o > 0; o >>= 1) lmax = fmaxf(lmax, __shfl_xor(lmax, o));
    if (lane == 0) red[wave] = lmax;
    __syncthreads();
    float m = fmaxf(fmaxf(red[0], red[1]), fmaxf(red[2], red[3]));
    __syncthreads();
    float lsum = 0.f;
#pragma unroll
    for (int r = 0; r < 2; ++r) {
        int i4 = tid + r * 256;
        if (i4 * 4 <= q)
#pragma unroll
            for (int e = 0; e < 4; ++e) {
                int k = i4 * 4 + e;
                if (k <= q) lsum += __expf(vals[r * 4 + e] - m);
            }
    }
#pragma unroll
    for (int o = 32; o > 0; o >>= 1) lsum += __shfl_xor(lsum, o);
    if (lane == 0) red[wave] = lsum;
    __syncthreads();
    float inv = 1.0f / (red[0] + red[1] + red[2] + red[3]);
    unsigned short* prow = (unsigned short*)row;
    int kmax = ((q >> 8) + 1) << 8;
#pragma unroll
    for (int r = 0; r < 2; ++r) {
        int i4 = tid + r * 256;
        if (i4 * 4 < kmax) {
            u16x4 o4;
#pragma unroll
            for (int e = 0; e < 4; ++e) {
                int k = i4 * 4 + e;
                float p = (k <= q) ? __expf(vals[r * 4 + e] - m) * inv : 0.0f;
                o4[e] = f2bf(p);
            }
            *(u16x4*)(prow + i4 * 4) = o4;
        }
    }
}

// ---------------- O = P @ V, exact-256-block split-K hybrid -----------------
// Blocks 0..63: mq 7,6 as 8p 256^2-tile K-halves (4 nd x 2 h x 4 b each) ->
//   partial stores to pp0/pp1 (rows 1536..2047 region, 8MB each, dead Qb/Kb).
//   mq7: Khalf=1024 (nkt=16, koff=h*2048B); mq6: Khalf=896 (nkt=14, koff=h*1792B).
// Blocks 64..255: mq 5..0 core8 whole-K (R15 path, rows <1536, direct store).
// Exactly 256 blocks = one round (fixes R16's 1.5-round quantization).
// reduce_tail then sums pp0+pp1 into O rows 1536..2047.
__global__ __launch_bounds__(512, 2) void pv_gemm(
    const bf16* __restrict__ P, const bf16* __restrict__ Vt,
    float* __restrict__ O, float* __restrict__ pp0, float* __restrict__ pp1)
{
    extern __shared__ char smem[];
    int g = blockIdx.x, tid = threadIdx.x;
    int lane = tid & 63, wave = tid >> 6;
    if (g < 64) {
        int mq = 7 - (g >> 5);                   // 7 then 6
        int w = g & 31;
        int h = w & 1, b = (w >> 1) & 3, nd = (w >> 3) & 3;
        int khalf = (mq == 7) ? 1024 : 896;      // elems
        int nkt = khalf >> 6;                    // 16 or 14
        size_t koff = (size_t)h * khalf * 2;     // bytes
        f32x4 acc[8][4] = {};
        gemm8p((const char*)P + ((size_t)b * SLEN + mq * 256) * 8192 + koff, 8192,
               (const char*)(Vt + ((size_t)b * ED + nd * 256) * SLEN) + koff, SLEN * 2,
               nkt, smem, tid, acc);

        int wm = wave >> 2, wn = wave & 3;
        int rl = (lane >> 4) * 4, cl = lane & 15;
        float* pp = h ? pp1 : pp0;
#pragma unroll
        for (int mf = 0; mf < 8; ++mf)
#pragma unroll
            for (int j = 0; j < 4; ++j) {
                int r = mq * 256 + wm * 128 + mf * 16 + rl + j;   // 1536..2047
#pragma unroll
                for (int nf = 0; nf < 4; ++nf) {
                    int c = nd * 256 + wn * 64 + nf * 16 + cl;
                    pp[(((size_t)b << 9) + (r - 1536)) * ED + c] = acc[mf][nf][j];
                }
            }
    } else {
        int w = g - 64;
        int mq = 5 - (w >> 5);                   // 5 down to 0 (longest first)
        int b = w & 3, nd = (w >> 2) & 7;
        f32x4 acc[4][4] = {};
        int nkt = (mq + 1) * 4;                  // causal: k < (mq+1)*256
        gemm_core8((const char*)P + ((size_t)b * SLEN + mq * 256) * 8192, 8192,
                   (const char*)(Vt + ((size_t)b * ED + nd * 128) * SLEN), SLEN * 2,
                   nkt, smem, tid, acc);

        int wm = wave >> 1, wn = wave & 1;
        int rl = (lane >> 4) * 4, cl = lane & 15;
        float* Ob = O + (size_t)b * SLEN * ED;
#pragma unroll
        for (int mf = 0; mf < 4; ++mf)
#pragma unroll
            for (int j = 0; j < 4; ++j) {
                int r = mq * 256 + wm * 64 + mf * 16 + rl + j;    // < 1536
#pragma unroll
                for (int nf = 0; nf < 4; ++nf) {
                    int c = nd * 128 + wn * 64 + nf * 16 + cl;
                    Ob[(size_t)r * ED + c] = acc[mf][nf][j];
                }
            }
    }
}

// ---------------- reduce: O[rows 1536..2047] = pp0 + pp1 --------------------
__global__ __launch_bounds__(256) void reduce_tail(
    const float* __restrict__ pp0, const float* __restrict__ pp1,
    float* __restrict__ O)
{
    int t = blockIdx.x * 256 + threadIdx.x;      // 524288 threads x float4
    int b = t >> 17, rem = t & 131071;           // 2^17 float4 per batch region
    const float4* p04 = (const float4*)pp0;
    const float4* p14 = (const float4*)pp1;
    float4* O4 = (float4*)O;
    size_t pi = ((size_t)b << 17) + rem;
    float4 a = p04[pi], c = p14[pi];
    O4[((size_t)b * SLEN + 1536) * (ED / 4) + rem] =
        make_float4(a.x + c.x, a.y + c.y, a.z + c.z, a.w + c.w);
}

extern "C" void kernel_launch(void* const* d_in, const int* in_sizes, int n_in,
                              void* d_out, int out_size, void* d_ws, size_t ws_size,
                              hipStream_t stream)
{
    const float* x  = (const float*)d_in[0];
    const float* wq = (const float*)d_in[1];
    const float* wk = (const float*)d_in[2];
    const float* wv = (const float*)d_in[3];
    float* out = (float*)d_out;

    char* ws = (char*)d_ws;
    bf16* xb  = (bf16*)(ws);                       // 16 MB
    bf16* wqb = (bf16*)(ws + 16777216);            // 2 MB
    bf16* wkb = (bf16*)(ws + 18874368);            // 2 MB
    bf16* wvb = (bf16*)(ws + 20971520);            // 2 MB
    bf16* Qb  = (bf16*)(ws + 23068672);            // 16 MB (pp0 post-qk)
    bf16* Kb  = (bf16*)(ws + 39845888);            // 16 MB (pp1 post-qk)
    bf16* Vt  = (bf16*)(ws + 56623104);            // 16 MB
    float* Sc = (float*)(ws + 73400320);           // 64 MB (P bf16 aliases this)
    float* pp0 = (float*)(ws + 23068672);          // dead Qb region post-qk
    float* pp1 = (float*)(ws + 39845888);          // dead Kb region post-qk

    (void)hipFuncSetAttribute((const void*)qkv_gemm,
            hipFuncAttributeMaxDynamicSharedMemorySize, 131072);
    (void)hipFuncSetAttribute((const void*)qk_gemm,
            hipFuncAttributeMaxDynamicSharedMemorySize, 131072);
    (void)hipFuncSetAttribute((const void*)pv_gemm,
            hipFuncAttributeMaxDynamicSharedMemorySize, 131072);

    convert_to_bf16<<<5632, 256, 0, stream>>>(x, wq, wk, wv, xb, wqb, wkb, wvb);
    qkv_gemm<<<512, 512, 131072, stream>>>(xb, wqb, wkb, wvb, Qb, Kb, Vt);
    qk_gemm<<<dim3(36, NB), 512, 131072, stream>>>(Qb, Kb, Sc);
    softmax_rows<<<dim3(SLEN, NB), 256, 0, stream>>>(Sc);
    pv_gemm<<<256, 512, 131072, stream>>>((const bf16*)Sc, Vt, out, pp0, pp1);
    reduce_tail<<<2048, 256, 0, stream>>>(pp0, pp1, out);
}

// Round 19
// 150.740 us; speedup vs baseline: 1.0223x; 1.0223x over previous
//
#include <hip/hip_runtime.h>
#include <hip/hip_bf16.h>
#include <stdint.h>

typedef __hip_bfloat16 bf16;
typedef __attribute__((ext_vector_type(8))) short bf16x8;
typedef __attribute__((ext_vector_type(4))) float f32x4;
typedef __attribute__((ext_vector_type(8))) unsigned short u16x8;
typedef __attribute__((ext_vector_type(4))) unsigned short u16x4;

#define SLEN 2048
#define ED   1024
#define NB   4
#define AS1 __attribute__((address_space(1)))
#define AS3 __attribute__((address_space(3)))
#define SB0() __builtin_amdgcn_sched_barrier(0)

static __device__ __forceinline__ unsigned short f2bf(float f) {
    return __builtin_bit_cast(unsigned short, __float2bfloat16(f));
}

// ============================================================================
// gemm8p (MEASURED PASSING R14-R18). 8-phase 256x256 / BK=64 / 512 thr.
// DO NOT MODIFY.
// ============================================================================
__device__ __forceinline__ void gemm8p(
    const char* __restrict__ aT, int lda,
    const char* __restrict__ bT, int ldb,
    int nkt, char* sm, int tid, f32x4 (&acc)[8][4])
{
    const int lane = tid & 63, wave = tid >> 6;
    const int wm = wave >> 2, wn = wave & 3;
    const int fr = lane & 15, kc = lane >> 4;

    auto SU = [&](int isB, int kh, int Tn) {
        char* dst = sm + (Tn & 1) * 65536 + isB * 32768 + kh * 16384;
        const char* g = isB ? bT : aT;
        const int ld = isB ? ldb : lda;
#pragma unroll
        for (int j = 0; j < 2; ++j) {
            int rid = j * 512 + tid;
            int row = rid >> 2, c = rid & 3;
            const char* src = g + (size_t)row * ld + Tn * 128 + kh * 64
                            + ((c ^ ((row >> 1) & 3)) * 16);
            __builtin_amdgcn_global_load_lds(
                (const AS1 uint32_t*)src,
                (AS3 uint32_t*)(dst + (j * 512 + wave * 64) * 16), 16, 0, 0);
        }
    };
    auto RDA = [&](int T, int kh, bf16x8 (&a)[8]) {
        const char* pa = sm + (T & 1) * 65536 + kh * 16384;
#pragma unroll
        for (int i = 0; i < 8; ++i) {
            int row = wm * 128 + i * 16 + fr;
            a[i] = *(const bf16x8*)(pa + row * 64 + ((kc ^ ((row >> 1) & 3)) * 16));
        }
    };
    auto RDB = [&](int T, int kh, int nh, bf16x8 (&b)[2]) {
        const char* pb = sm + (T & 1) * 65536 + 32768 + kh * 16384;
#pragma unroll
        for (int n = 0; n < 2; ++n) {
            int row = wn * 64 + nh * 32 + n * 16 + fr;
            b[n] = *(const bf16x8*)(pb + row * 64 + ((kc ^ ((row >> 1) & 3)) * 16));
        }
    };
    auto MM = [&](bf16x8 (&a)[8], bf16x8 (&b)[2], int nh) {
        __builtin_amdgcn_s_setprio(1);
#pragma unroll
        for (int i = 0; i < 8; ++i)
#pragma unroll
            for (int n = 0; n < 2; ++n)
                acc[i][nh * 2 + n] = __builtin_amdgcn_mfma_f32_16x16x32_bf16(
                    a[i], b[n], acc[i][nh * 2 + n], 0, 0, 0);
        __builtin_amdgcn_s_setprio(0);
    };

    SU(0, 0, 0); SU(1, 0, 0); SU(0, 1, 0); SU(1, 1, 0);
    SU(0, 0, 1); SU(1, 0, 1); SU(0, 1, 1);
    asm volatile("s_waitcnt vmcnt(6)" ::: "memory");
    SB0();
    __builtin_amdgcn_s_barrier();

    for (int T = 0; T < nkt; ++T) {
        const bool p1 = (T + 1 < nkt), p2 = (T + 2 < nkt);
        bf16x8 a[8], b[2];
        RDA(T, 0, a); RDB(T, 0, 0, b);
        if (p1) SU(1, 1, T + 1);
        SB0(); __builtin_amdgcn_s_barrier();
        asm volatile("s_waitcnt lgkmcnt(0)" ::: "memory");
        SB0();
        MM(a, b, 0);
        SB0(); __builtin_amdgcn_s_barrier();
        RDB(T, 0, 1, b);
        if (p2) SU(0, 0, T + 2);
        SB0(); __builtin_amdgcn_s_barrier();
        asm volatile("s_waitcnt lgkmcnt(0)" ::: "memory");
        SB0();
        MM(a, b, 1);
        SB0(); __builtin_amdgcn_s_barrier();
        RDA(T, 1, a); RDB(T, 1, 0, b);
        if (p2) SU(1, 0, T + 2);
        SB0(); __builtin_amdgcn_s_barrier();
        asm volatile("s_waitcnt lgkmcnt(0)" ::: "memory");
        SB0();
        MM(a, b, 0);
        SB0(); __builtin_amdgcn_s_barrier();
        RDB(T, 1, 1, b);
        if (p2) SU(0, 1, T + 2);
        if (T < nkt - 2) asm volatile("s_waitcnt vmcnt(6)" ::: "memory");
        else             asm volatile("s_waitcnt vmcnt(0)" ::: "memory");
        SB0(); __builtin_amdgcn_s_barrier();
        asm volatile("s_waitcnt lgkmcnt(0)" ::: "memory");
        SB0();
        MM(a, b, 1);
        SB0(); __builtin_amdgcn_s_barrier();
    }
}

// ============================================================================
// gemm_core8 (MEASURED PASSING R7): 256x128 / 512 thr. DO NOT MODIFY.
// ============================================================================
__device__ __forceinline__ void gemm_core8(
    const char* __restrict__ aT, int lda,
    const char* __restrict__ bT, int ldb,
    int nkt, char* sm, int tid, f32x4 (&acc)[4][4])
{
    const int lane = tid & 63, wave = tid >> 6;
    const int wm = wave >> 1, wn = wave & 1;
    const int fr = lane & 15, kc = lane >> 4;

    auto STAGE = [&](int kh, int Tn) {
        char* buf = sm + (Tn & 1) * 49152;
#pragma unroll
        for (int j = 0; j < 2; ++j) {
            int rid = j * 512 + tid;
            int row = rid >> 2, c = rid & 3;
            const char* src = aT + (size_t)row * lda + Tn * 128 + kh * 64
                            + ((c ^ ((row >> 1) & 3)) * 16);
            __builtin_amdgcn_global_load_lds(
                (const AS1 uint32_t*)src,
                (AS3 uint32_t*)(buf + kh * 16384 + (j * 512 + wave * 64) * 16),
                16, 0, 0);
        }
        {
            int row = tid >> 2, c = tid & 3;
            const char* src = bT + (size_t)row * ldb + Tn * 128 + kh * 64
                            + ((c ^ ((row >> 1) & 3)) * 16);
            __builtin_amdgcn_global_load_lds(
                (const AS1 uint32_t*)src,
                (AS3 uint32_t*)(buf + 32768 + kh * 8192 + (wave * 64) * 16),
                16, 0, 0);
        }
    };
    auto RD = [&](int T, int kh, bf16x8 (&a)[4], bf16x8 (&b)[4]) {
        const char* buf = sm + (T & 1) * 49152;
#pragma unroll
        for (int i = 0; i < 4; ++i) {
            int row = wm * 64 + i * 16 + fr;
            a[i] = *(const bf16x8*)(buf + kh * 16384 + row * 64
                                    + ((kc ^ ((row >> 1) & 3)) * 16));
        }
#pragma unroll
        for (int i = 0; i < 4; ++i) {
            int row = wn * 64 + i * 16 + fr;
            b[i] = *(const bf16x8*)(buf + 32768 + kh * 8192 + row * 64
                                    + ((kc ^ ((row >> 1) & 3)) * 16));
        }
    };
    auto MM = [&](bf16x8 (&a)[4], bf16x8 (&b)[4]) {
        __builtin_amdgcn_s_setprio(1);
#pragma unroll
        for (int i = 0; i < 4; ++i)
#pragma unroll
            for (int n = 0; n < 4; ++n)
                acc[i][n] = __builtin_amdgcn_mfma_f32_16x16x32_bf16(
                    a[i], b[n], acc[i][n], 0, 0, 0);
        __builtin_amdgcn_s_setprio(0);
    };

    STAGE(0, 0); STAGE(1, 0);
    asm volatile("s_waitcnt vmcnt(3)" ::: "memory");
    SB0();
    __builtin_amdgcn_s_barrier();

    bf16x8 aE[4], bE[4], aO[4], bO[4];
    for (int T = 0; T < nkt; ++T) {
        const bool pre = (T + 1 < nkt);
        RD(T, 0, aE, bE);
        SB0();
        if (pre) STAGE(0, T + 1);
        SB0();
        if (T > 0) {
            asm volatile("s_waitcnt lgkmcnt(8)" ::: "memory");
            SB0();
            MM(aO, bO);
        }
        if (pre) asm volatile("s_waitcnt vmcnt(3)" ::: "memory");
        else     asm volatile("s_waitcnt vmcnt(0)" ::: "memory");
        SB0();
        __builtin_amdgcn_s_barrier();
        RD(T, 1, aO, bO);
        SB0();
        if (pre) STAGE(1, T + 1);
        SB0();
        asm volatile("s_waitcnt lgkmcnt(8)" ::: "memory");
        SB0();
        MM(aE, bE);
        if (pre) asm volatile("s_waitcnt vmcnt(3)" ::: "memory");
        else     asm volatile("s_waitcnt vmcnt(0)" ::: "memory");
        SB0();
        __builtin_amdgcn_s_barrier();
    }
    asm volatile("s_waitcnt lgkmcnt(0)" ::: "memory");
    SB0();
    MM(aO, bO);
}

// ---------------- convert fp32 -> bf16 (x and the 3 weights) ----------------
__global__ __launch_bounds__(256) void convert_to_bf16(
    const float* __restrict__ x, const float* __restrict__ wq,
    const float* __restrict__ wk, const float* __restrict__ wv,
    bf16* __restrict__ xb, bf16* __restrict__ wqb,
    bf16* __restrict__ wkb, bf16* __restrict__ wvb)
{
    long g = (long)blockIdx.x * 256 + threadIdx.x;
    const float* src; bf16* dst; long o;
    if (g < 1048576) { src = x; dst = xb; o = g * 8; }
    else {
        long g2 = g - 1048576;
        int w = (int)(g2 >> 17);
        o = (g2 & 131071) * 8;
        src = (w == 0) ? wq : (w == 1) ? wk : wv;
        dst = (w == 0) ? wqb : (w == 1) ? wkb : wvb;
    }
    float4 v0 = *(const float4*)(src + o);
    float4 v1 = *(const float4*)(src + o + 4);
    u16x8 r;
    r[0] = f2bf(v0.x); r[1] = f2bf(v0.y); r[2] = f2bf(v0.z); r[3] = f2bf(v0.w);
    r[4] = f2bf(v1.x); r[5] = f2bf(v1.y); r[6] = f2bf(v1.z); r[7] = f2bf(v1.w);
    *(u16x8*)(dst + o) = r;
}

// ---------------- fused QKV (R17 verbatim, 59.1us measured): 512 blocks -----
__global__ __launch_bounds__(512, 2) void qkv_gemm(
    const bf16* __restrict__ xb, const bf16* __restrict__ wqb,
    const bf16* __restrict__ wkb, const bf16* __restrict__ wvb,
    bf16* __restrict__ Qb, bf16* __restrict__ Kb, bf16* __restrict__ Vt)
{
    extern __shared__ char smem[];
    int bid = blockIdx.x, tid = threadIdx.x;
    int lane = tid & 63, wave = tid >> 6;
    if (bid < 256) {
        int xcd = bid & 7, i = bid >> 3;
        int tm = (xcd << 2) | (i & 3);
        int tn = i >> 2;
        const bf16* W = (tn < 4) ? wqb : wkb;
        int tnl = tn & 3;
        f32x4 acc[8][4] = {};
        gemm8p((const char*)(xb + (size_t)tm * 256 * ED), ED * 2,
               (const char*)(W + (size_t)tnl * 256 * ED), ED * 2,
               16, smem, tid, acc);

        int wm = wave >> 2, wn = wave & 3;
        int rl = (lane >> 4) * 4, cl = lane & 15;
        bf16* C = (tn < 4) ? Qb : Kb;
#pragma unroll
        for (int mf = 0; mf < 8; ++mf)
#pragma unroll
            for (int j = 0; j < 4; ++j) {
                int r = tm * 256 + wm * 128 + mf * 16 + rl + j;
#pragma unroll
                for (int nf = 0; nf < 4; ++nf) {
                    int c = tnl * 256 + wn * 64 + nf * 16 + cl;
                    C[(size_t)r * ED + c] = __float2bfloat16(acc[mf][nf][j]);
                }
            }
    } else {
        int bid2 = bid - 256;
        int xcd = bid2 & 7, i = bid2 >> 3;
        int tm = (xcd << 2) | (i & 3);
        int tnl = i >> 2;
        f32x4 acc[4][4] = {};
        gemm_core8((const char*)(xb + (size_t)tm * 256 * ED), ED * 2,
                   (const char*)(wvb + (size_t)tnl * 128 * ED), ED * 2,
                   16, smem, tid, acc);

        int wm = wave >> 1, wn = wave & 1;
        int rl = (lane >> 4) * 4, cl = lane & 15;
#pragma unroll
        for (int mf = 0; mf < 4; ++mf)
#pragma unroll
            for (int j = 0; j < 4; ++j) {
                int r = tm * 256 + wm * 64 + mf * 16 + rl + j;
                int bb = r >> 11, s = r & 2047;
#pragma unroll
                for (int nf = 0; nf < 4; ++nf) {
                    int d = tnl * 128 + wn * 64 + nf * 16 + cl;
                    Vt[(((size_t)bb << 10) + d) * SLEN + s] = __float2bfloat16(acc[mf][nf][j]);
                }
            }
    }
}

// ---------------- scores = Q @ K^T / 32: 144 blocks, XCD-swizzled -----------
// Flatten 144 = 8*18: swz=(g%8)*18+g/8 (bijective). Each XCD owns 18
// consecutive (b,t) indices -> neighboring ti/tj share Q/K panels in its L2.
__global__ __launch_bounds__(512, 2) void qk_gemm(
    const bf16* __restrict__ Qb, const bf16* __restrict__ Kb, float* __restrict__ Sc)
{
    extern __shared__ char smem[];
    int g = blockIdx.x, tid = threadIdx.x;
    int swz = (g & 7) * 18 + (g >> 3);           // 144 = 8*18, bijective
    int b = swz / 36, t = swz % 36;
    int ti = 0;
    while ((ti + 1) * (ti + 2) / 2 <= t) ++ti;   // triangular decode, ti<=7
    int tj = t - ti * (ti + 1) / 2;
    f32x4 acc[8][4] = {};
    gemm8p((const char*)(Qb + ((size_t)b * SLEN + ti * 256) * ED), ED * 2,
           (const char*)(Kb + ((size_t)b * SLEN + tj * 256) * ED), ED * 2,
           16, smem, tid, acc);

    float* Sb = Sc + (size_t)b * SLEN * SLEN;
    int lane = tid & 63, wave = tid >> 6, wm = wave >> 2, wn = wave & 3;
    int rl = (lane >> 4) * 4, cl = lane & 15;
#pragma unroll
    for (int mf = 0; mf < 8; ++mf)
#pragma unroll
        for (int j = 0; j < 4; ++j) {
            int r = ti * 256 + wm * 128 + mf * 16 + rl + j;
#pragma unroll
            for (int nf = 0; nf < 4; ++nf) {
                int c = tj * 256 + wn * 64 + nf * 16 + cl;
                Sb[(size_t)r * SLEN + c] = acc[mf][nf][j] * 0.03125f;
            }
        }
}

// ---------------- causal row softmax (R15 verbatim, kmax-trimmed) -----------
__global__ __launch_bounds__(256) void softmax_rows(float* __restrict__ Sc)
{
    int q = blockIdx.x, b = blockIdx.y, tid = threadIdx.x;
    float* row = Sc + ((size_t)b * SLEN + q) * SLEN;
    int lane = tid & 63, wave = tid >> 6;
    __shared__ float red[4];

    float vals[8];
    float lmax = -3.0e38f;
#pragma unroll
    for (int r = 0; r < 2; ++r) {
        int i4 = tid + r * 256;
        if (i4 * 4 <= q) {
            float4 v = *(const float4*)(row + i4 * 4);
            vals[r * 4 + 0] = v.x; vals[r * 4 + 1] = v.y;
            vals[r * 4 + 2] = v.z; vals[r * 4 + 3] = v.w;
#pragma unroll
            for (int e = 0; e < 4; ++e) {
                int k = i4 * 4 + e;
                if (k <= q) lmax = fmaxf(lmax, vals[r * 4 + e]);
            }
        }
    }
#pragma unroll
    for (int o = 32; o > 0; o >>= 1) lmax = fmaxf(lmax, __shfl_xor(lmax, o));
    if (lane == 0) red[wave] = lmax;
    __syncthreads();
    float m = fmaxf(fmaxf(red[0], red[1]), fmaxf(red[2], red[3]));
    __syncthreads();
    float lsum = 0.f;
#pragma unroll
    for (int r = 0; r < 2; ++r) {
        int i4 = tid + r * 256;
        if (i4 * 4 <= q)
#pragma unroll
            for (int e = 0; e < 4; ++e) {
                int k = i4 * 4 + e;
                if (k <= q) lsum += __expf(vals[r * 4 + e] - m);
            }
    }
#pragma unroll
    for (int o = 32; o > 0; o >>= 1) lsum += __shfl_xor(lsum, o);
    if (lane == 0) red[wave] = lsum;
    __syncthreads();
    float inv = 1.0f / (red[0] + red[1] + red[2] + red[3]);
    unsigned short* prow = (unsigned short*)row;
    int kmax = ((q >> 8) + 1) << 8;
#pragma unroll
    for (int r = 0; r < 2; ++r) {
        int i4 = tid + r * 256;
        if (i4 * 4 < kmax) {
            u16x4 o4;
#pragma unroll
            for (int e = 0; e < 4; ++e) {
                int k = i4 * 4 + e;
                float p = (k <= q) ? __expf(vals[r * 4 + e] - m) * inv : 0.0f;
                o4[e] = f2bf(p);
            }
            *(u16x4*)(prow + i4 * 4) = o4;
        }
    }
}

// ---------------- O = P @ V: 256 blocks, XCD-swizzled -----------------------
// Flatten 256 = 8*32: swz=(g%8)*32+g/8 (bijective). Each XCD owns one mq
// stripe (32 consecutive swz = same mq, all nd/b) -> P row panels re-read
// from its private L2 instead of HBM.
__global__ __launch_bounds__(512, 2) void pv_gemm(
    const bf16* __restrict__ P, const bf16* __restrict__ Vt, float* __restrict__ O)
{
    extern __shared__ char smem[];
    int g = blockIdx.x, tid = threadIdx.x;
    int swz = (g & 7) * 32 + (g >> 3);           // 256 = 8*32, bijective
    int mq = 7 - (swz >> 5);                     // longest-K stripes first
    int rest = swz & 31;
    int nd = rest >> 2, b = rest & 3;
    f32x4 acc[4][4] = {};
    int nkt = (mq + 1) * 4;                      // causal: k < (mq+1)*256
    gemm_core8((const char*)P + ((size_t)b * SLEN + mq * 256) * 8192, 8192,
               (const char*)(Vt + ((size_t)b * ED + nd * 128) * SLEN), SLEN * 2,
               nkt, smem, tid, acc);

    int lane = tid & 63, wave = tid >> 6, wm = wave >> 1, wn = wave & 1;
    int rl = (lane >> 4) * 4, cl = lane & 15;
    float* Ob = O + (size_t)b * SLEN * ED;
#pragma unroll
    for (int mf = 0; mf < 4; ++mf)
#pragma unroll
        for (int j = 0; j < 4; ++j) {
            int r = mq * 256 + wm * 64 + mf * 16 + rl + j;
#pragma unroll
            for (int nf = 0; nf < 4; ++nf) {
                int c = nd * 128 + wn * 64 + nf * 16 + cl;
                Ob[(size_t)r * ED + c] = acc[mf][nf][j];
            }
        }
}

extern "C" void kernel_launch(void* const* d_in, const int* in_sizes, int n_in,
                              void* d_out, int out_size, void* d_ws, size_t ws_size,
                              hipStream_t stream)
{
    const float* x  = (const float*)d_in[0];
    const float* wq = (const float*)d_in[1];
    const float* wk = (const float*)d_in[2];
    const float* wv = (const float*)d_in[3];
    float* out = (float*)d_out;

    char* ws = (char*)d_ws;
    bf16* xb  = (bf16*)(ws);                       // 16 MB
    bf16* wqb = (bf16*)(ws + 16777216);            // 2 MB
    bf16* wkb = (bf16*)(ws + 18874368);            // 2 MB
    bf16* wvb = (bf16*)(ws + 20971520);            // 2 MB
    bf16* Qb  = (bf16*)(ws + 23068672);            // 16 MB
    bf16* Kb  = (bf16*)(ws + 39845888);            // 16 MB
    bf16* Vt  = (bf16*)(ws + 56623104);            // 16 MB
    float* Sc = (float*)(ws + 73400320);           // 64 MB (P bf16 aliases this)

    (void)hipFuncSetAttribute((const void*)qkv_gemm,
            hipFuncAttributeMaxDynamicSharedMemorySize, 131072);
    (void)hipFuncSetAttribute((const void*)qk_gemm,
            hipFuncAttributeMaxDynamicSharedMemorySize, 131072);
    (void)hipFuncSetAttribute((const void*)pv_gemm,
            hipFuncAttributeMaxDynamicSharedMemorySize, 98304);

    convert_to_bf16<<<5632, 256, 0, stream>>>(x, wq, wk, wv, xb, wqb, wkb, wvb);
    qkv_gemm<<<512, 512, 131072, stream>>>(xb, wqb, wkb, wvb, Qb, Kb, Vt);
    qk_gemm<<<144, 512, 131072, stream>>>(Qb, Kb, Sc);
    softmax_rows<<<dim3(SLEN, NB), 256, 0, stream>>>(Sc);
    pv_gemm<<<256, 512, 98304, stream>>>((const bf16*)Sc, Vt, out);
}